// Round 1
// baseline (402.733 us; speedup 1.0000x reference)
//
#include <hip/hip_runtime.h>

// Problem constants (from reference): B=4096, F=32, C=128, orders 1..3
constexpr int B_   = 4096;
constexpr int F_   = 32;
constexpr int C_   = 128;
constexpr int K1   = 32;      // C(32,1)
constexpr int K2   = 496;     // C(32,2)
constexpr int K3   = 4960;    // C(32,3)
constexpr int KTOT = K1 + K2 + K3;   // 5488

// Tiling
constexpr int BM     = 128;   // rows per block
constexpr int KC     = 32;    // K chunk
constexpr int SPLITK = 8;     // K split -> grid = 32 x 8 = 256 blocks
constexpr int KSEG   = KTOT / SPLITK;  // 686 (exact)

// LDS strides (floats)
constexpr int XS  = 33;    // x tile row stride: 32 feats + 1.0 pad; 33 => conflict-free
constexpr int PS  = 132;   // P_s row stride (128 + 4, keeps float4 alignment)
constexpr int WSD = 132;   // W_s row stride

// prep: out = bias (broadcast), build unified index table in ws
__global__ __launch_bounds__(256)
void prep_kernel(const float* __restrict__ bias,
                 const int* __restrict__ idx1,
                 const int* __restrict__ idx2,
                 const int* __restrict__ idx3,
                 float* __restrict__ out,
                 int4* __restrict__ u_idx)
{
    int i = blockIdx.x * 256 + threadIdx.x;
    if (i < B_ * C_) out[i] = bias[i & (C_ - 1)];
    if (i < KTOT) {
        int4 v; v.w = 0;
        if (i < K1) {
            v.x = idx1[i]; v.y = F_; v.z = F_;          // F_ -> x_s pad slot == 1.0f
        } else if (i < K1 + K2) {
            int j = i - K1;
            v.x = idx2[2 * j]; v.y = idx2[2 * j + 1]; v.z = F_;
        } else {
            int j = i - K1 - K2;
            v.x = idx3[3 * j]; v.y = idx3[3 * j + 1]; v.z = idx3[3 * j + 2];
        }
        u_idx[i] = v;
    }
}

// main: fused product construction + GEMM, split-K, atomic epilogue
__global__ __launch_bounds__(256, 2)
void poly_gemm(const float* __restrict__ x,
               const float* __restrict__ W1,
               const float* __restrict__ W2,
               const float* __restrict__ W3,
               const int4* __restrict__ u_idx,
               float* __restrict__ out)
{
    __shared__ float x_s[BM * XS];
    __shared__ float P_s[KC * PS];
    __shared__ float W_s[KC * WSD];

    const int t    = threadIdx.x;
    const int row0 = blockIdx.x * BM;
    const int kbeg = blockIdx.y * KSEG;
    const int kend = kbeg + KSEG;

    // Load x tile [BM][32], coalesced; pad col 32 with 1.0f
    for (int i = t; i < BM * F_; i += 256) {
        int r = i >> 5, f = i & 31;
        x_s[r * XS + f] = x[(row0 + r) * F_ + f];
    }
    for (int r = t; r < BM; r += 256) x_s[r * XS + F_] = 1.0f;

    float acc[8][8];
    #pragma unroll
    for (int i = 0; i < 8; ++i)
        #pragma unroll
        for (int j = 0; j < 8; ++j) acc[i][j] = 0.f;

    const int cg    = t & 15;   // col group: cols cg*8 .. cg*8+7
    const int rg    = t >> 4;   // row group: rows rg*8 .. rg*8+7
    const int rr    = t & 127;  // product row
    const int khalf = t >> 7;   // 0/1: which k parity this thread builds

    for (int kc = kbeg; kc < kend; kc += KC) {
        __syncthreads();  // prior iter's P_s/W_s reads done; x_s ready on iter 0

        // Stage W chunk [KC][128] (coalesced across c), zero-fill past kend
        #pragma unroll
        for (int i = 0; i < 16; ++i) {
            int e  = t + i * 256;
            int kk = e >> 7, c = e & 127;
            int k  = kc + kk;
            float w = 0.f;
            if (k < kend) {
                if (k < K1)           w = W1[k * C_ + c];
                else if (k < K1 + K2) w = W2[(k - K1) * C_ + c];
                else                  w = W3[(k - K1 - K2) * C_ + c];
            }
            W_s[kk * WSD + c] = w;
        }

        // Build products P_s[kk][r] = prod(x[r, subset]) ; zero past kend
        {
            const float* xr = &x_s[rr * XS];
            #pragma unroll
            for (int i = 0; i < 16; ++i) {
                int kk = khalf + 2 * i;
                int k  = kc + kk;
                float p = 0.f;
                if (k < kend) {
                    int4 id = u_idx[k];  // wave-uniform k -> broadcast
                    p = xr[id.x] * xr[id.y] * xr[id.z];
                }
                P_s[kk * PS + rr] = p;
            }
        }
        __syncthreads();

        // 8x8 register micro-tile FMAs
        #pragma unroll 4
        for (int kk = 0; kk < KC; ++kk) {
            float4 p0 = *(const float4*)&P_s[kk * PS + rg * 8];
            float4 p1 = *(const float4*)&P_s[kk * PS + rg * 8 + 4];
            float4 w0 = *(const float4*)&W_s[kk * WSD + cg * 8];
            float4 w1 = *(const float4*)&W_s[kk * WSD + cg * 8 + 4];
            float p[8] = {p0.x, p0.y, p0.z, p0.w, p1.x, p1.y, p1.z, p1.w};
            float w[8] = {w0.x, w0.y, w0.z, w0.w, w1.x, w1.y, w1.z, w1.w};
            #pragma unroll
            for (int i = 0; i < 8; ++i)
                #pragma unroll
                for (int j = 0; j < 8; ++j)
                    acc[i][j] = fmaf(p[i], w[j], acc[i][j]);
        }
    }

    // Epilogue: atomic accumulate partial K sums into out (pre-initialized with bias)
    #pragma unroll
    for (int i = 0; i < 8; ++i) {
        int r = row0 + rg * 8 + i;
        float* o = &out[r * C_ + cg * 8];
        #pragma unroll
        for (int j = 0; j < 8; ++j)
            atomicAdd(o + j, acc[i][j]);
    }
}

extern "C" void kernel_launch(void* const* d_in, const int* in_sizes, int n_in,
                              void* d_out, int out_size, void* d_ws, size_t ws_size,
                              hipStream_t stream)
{
    const float* x    = (const float*)d_in[0];
    const float* bias = (const float*)d_in[1];
    const float* W1   = (const float*)d_in[2];
    const float* W2   = (const float*)d_in[3];
    const float* W3   = (const float*)d_in[4];
    const int*   idx1 = (const int*)d_in[5];
    const int*   idx2 = (const int*)d_in[6];
    const int*   idx3 = (const int*)d_in[7];
    float* out  = (float*)d_out;
    int4* u_idx = (int4*)d_ws;   // 5488 * 16 B = ~88 KB of scratch

    int prep_blocks = (B_ * C_ + 255) / 256;
    prep_kernel<<<prep_blocks, 256, 0, stream>>>(bias, idx1, idx2, idx3, out, u_idx);

    dim3 grid(B_ / BM, SPLITK);
    poly_gemm<<<grid, 256, 0, stream>>>(x, W1, W2, W3, u_idx, out);
}

// Round 2
// 128.029 us; speedup vs baseline: 3.1456x; 3.1456x over previous
//
#include <hip/hip_runtime.h>
#include <hip/hip_bf16.h>

// Problem: out[4096,128] = bias + P @ W, P built from products of x-subsets
constexpr int B_   = 4096;
constexpr int C_   = 128;
constexpr int K1   = 32;
constexpr int K2   = 496;
constexpr int K3   = 4960;
constexpr int KTOT = K1 + K2 + K3;   // 5488
constexpr int KPAD = 5632;           // 16 * 352, pad entries produce p=0, w=0

constexpr int SPLITK = 16;
constexpr int KSEG   = KPAD / SPLITK;  // 352
constexpr int KC     = 32;             // one mfma K per chunk
constexpr int CHUNKS = KSEG / KC;      // 11
constexpr int BM     = 64;             // rows per block

constexpr int XS = 35;   // x_s row stride (floats): 32 feats + [32]=1.0 + [33]=0.0; odd -> conflict-free
constexpr int PW = 40;   // P_s/W_s k-stride (bf16): 80 B = 5*16B odd superbank -> conflict-free b128

typedef __attribute__((ext_vector_type(8))) short bf16x8;  // 8 bf16 in 4 VGPRs
typedef __attribute__((ext_vector_type(4))) float f32x4;

// ws layout
constexpr size_t WS_IDX_OFF = 0;                 // int4[KPAD]  = 90112 B
constexpr size_t WS_WT_OFF  = 98304;             // ushort[C_ * KPAD] = 1441792 B

// prep 1: out = bias broadcast; build padded unified index table
__global__ __launch_bounds__(256)
void prep_misc(const float* __restrict__ bias,
               const int* __restrict__ idx1,
               const int* __restrict__ idx2,
               const int* __restrict__ idx3,
               float* __restrict__ out,
               int4* __restrict__ u_idx)
{
    int i = blockIdx.x * 256 + threadIdx.x;
    if (i < B_ * C_) out[i] = bias[i & (C_ - 1)];
    if (i < KPAD) {
        int4 v; v.w = 0;
        if (i < K1)            { v.x = idx1[i];        v.y = 32; v.z = 32; }   // x_s[32]=1.0
        else if (i < K1 + K2)  { int j = i - K1;       v.x = idx2[2*j];   v.y = idx2[2*j+1]; v.z = 32; }
        else if (i < KTOT)     { int j = i - K1 - K2;  v.x = idx3[3*j];   v.y = idx3[3*j+1]; v.z = idx3[3*j+2]; }
        else                   { v.x = 33; v.y = 33; v.z = 33; }               // x_s[33]=0.0 -> p=0
        u_idx[i] = v;
    }
}

// prep 2: W (fp32, [k][c]) -> Wb_t (bf16, [c][k]) via LDS tile transpose; zero pads
__global__ __launch_bounds__(256)
void prep_wt(const float* __restrict__ W1,
             const float* __restrict__ W2,
             const float* __restrict__ W3,
             ushort* __restrict__ Wb)
{
    __shared__ ushort tile[64 * 132];
    const int k0 = blockIdx.x * 64;
    const int t  = threadIdx.x;
    #pragma unroll 4
    for (int p = 0; p < 32; ++p) {              // read coalesced over c
        int e = p * 256 + t;
        int kk = e >> 7, c = e & 127;
        int k = k0 + kk;
        float v = 0.f;
        if (k < K1)           v = W1[k * C_ + c];
        else if (k < K1 + K2) v = W2[(k - K1) * C_ + c];
        else if (k < KTOT)    v = W3[(k - K1 - K2) * C_ + c];
        __hip_bfloat16 h = __float2bfloat16(v);
        tile[kk * 132 + c] = *reinterpret_cast<ushort*>(&h);
    }
    __syncthreads();
    #pragma unroll 4
    for (int p = 0; p < 32; ++p) {              // write coalesced over k
        int e = p * 256 + t;
        int c = e >> 6, kk = e & 63;
        Wb[(size_t)c * KPAD + k0 + kk] = tile[kk * 132 + c];
    }
}

// main: fused product construction + bf16 MFMA GEMM, split-K, atomic epilogue
__global__ __launch_bounds__(256, 4)
void poly_mfma(const float* __restrict__ x,
               const int4* __restrict__ u_idx,
               const ushort* __restrict__ Wb,
               float* __restrict__ out)
{
    __shared__ float  x_s[BM * XS];     //  8960 B
    __shared__ ushort P_s[BM * PW];     //  5120 B  [row][k] bf16
    __shared__ ushort W_s[C_ * PW];     // 10240 B  [col][k] bf16 (= W^T chunk)

    const int t    = threadIdx.x;
    const int row0 = blockIdx.x * BM;
    const int kbeg = blockIdx.y * KSEG;

    // stage x tile [64][32] + constants
    #pragma unroll
    for (int p = 0; p < 2; ++p) {
        int e = p * 256 + t;            // r = e>>3, q = e&7
        int r = e >> 3, q = e & 7;
        float4 v = ((const float4*)x)[(size_t)(row0 + r) * 8 + q];
        float* d = &x_s[r * XS + q * 4];
        d[0] = v.x; d[1] = v.y; d[2] = v.z; d[3] = v.w;
    }
    if (t < BM) { x_s[t * XS + 32] = 1.0f; x_s[t * XS + 33] = 0.0f; }

    f32x4 acc[4][2];
    #pragma unroll
    for (int rt = 0; rt < 4; ++rt)
        #pragma unroll
        for (int ct = 0; ct < 2; ++ct) acc[rt][ct] = (f32x4){0.f, 0.f, 0.f, 0.f};

    const int lane = t & 63;
    const int w    = t >> 6;            // wave id 0..3 -> cols [w*32, w*32+32)
    const int m    = lane & 15;
    const int kg   = lane >> 4;         // 0..3: k-subgroup for frags
    const float* xr = &x_s[lane * XS];

    for (int ch = 0; ch < CHUNKS; ++ch) {
        const int kc = kbeg + ch * KC;
        __syncthreads();                // prior frag reads done; x_s ready on iter 0

        // stage W^T chunk: W_s[c][0..31], 2x b128 per thread
        #pragma unroll
        for (int p = 0; p < 2; ++p) {
            int e = p * 256 + t;
            int c = e >> 2, g = e & 3;
            *(uint4*)&W_s[c * PW + g * 8] =
                *(const uint4*)&Wb[(size_t)c * KPAD + kc + g * 8];
        }

        // build products: wave w owns contiguous k-run [kc+w*8, kc+w*8+8), row = lane
        {
            int pa = -1, pb = -1;
            float pab = 0.f;
            union { ushort us[8]; uint4 v; } pk;
            #pragma unroll
            for (int i = 0; i < 8; ++i) {
                int4 id = u_idx[kc + w * 8 + i];    // wave-uniform -> broadcast
                if (id.x != pa || id.y != pb) {     // lexicographic runs share (a,b)
                    pab = xr[id.x] * xr[id.y];
                    pa = id.x; pb = id.y;
                }
                float p = pab * xr[id.z];
                __hip_bfloat16 h = __float2bfloat16(p);
                pk.us[i] = *reinterpret_cast<ushort*>(&h);
            }
            *(uint4*)&P_s[lane * PW + w * 8] = pk.v;   // one b128, conflict-free
        }
        __syncthreads();

        // fragments + 8 MFMAs (64 rows x 32 cols per wave)
        bf16x8 a[4], b[2];
        #pragma unroll
        for (int rt = 0; rt < 4; ++rt)
            a[rt] = *(const bf16x8*)&P_s[(rt * 16 + m) * PW + kg * 8];
        #pragma unroll
        for (int ct = 0; ct < 2; ++ct)
            b[ct] = *(const bf16x8*)&W_s[(w * 32 + ct * 16 + m) * PW + kg * 8];
        #pragma unroll
        for (int rt = 0; rt < 4; ++rt)
            #pragma unroll
            for (int ct = 0; ct < 2; ++ct)
                acc[rt][ct] = __builtin_amdgcn_mfma_f32_16x16x32_bf16(
                    a[rt], b[ct], acc[rt][ct], 0, 0, 0);
    }

    // epilogue: atomic accumulate split-K partials (out pre-initialized with bias)
    const int rq = lane >> 4;           // C/D layout: col = lane&15, row = rq*4 + i
    #pragma unroll
    for (int rt = 0; rt < 4; ++rt)
        #pragma unroll
        for (int ct = 0; ct < 2; ++ct) {
            int col = w * 32 + ct * 16 + m;
            #pragma unroll
            for (int i = 0; i < 4; ++i) {
                int row = row0 + rt * 16 + rq * 4 + i;
                atomicAdd(&out[(size_t)row * C_ + col], acc[rt][ct][i]);
            }
        }
}

extern "C" void kernel_launch(void* const* d_in, const int* in_sizes, int n_in,
                              void* d_out, int out_size, void* d_ws, size_t ws_size,
                              hipStream_t stream)
{
    const float* x    = (const float*)d_in[0];
    const float* bias = (const float*)d_in[1];
    const float* W1   = (const float*)d_in[2];
    const float* W2   = (const float*)d_in[3];
    const float* W3   = (const float*)d_in[4];
    const int*   idx1 = (const int*)d_in[5];
    const int*   idx2 = (const int*)d_in[6];
    const int*   idx3 = (const int*)d_in[7];
    float* out  = (float*)d_out;

    int4*   u_idx = (int4*)((char*)d_ws + WS_IDX_OFF);
    ushort* Wb    = (ushort*)((char*)d_ws + WS_WT_OFF);   // ~1.54 MB total ws use

    prep_misc<<<(B_ * C_ + 255) / 256, 256, 0, stream>>>(bias, idx1, idx2, idx3, out, u_idx);
    prep_wt<<<KPAD / 64, 256, 0, stream>>>(W1, W2, W3, Wb);

    dim3 grid(B_ / BM, SPLITK);
    poly_mfma<<<grid, 256, 0, stream>>>(x, u_idx, Wb, out);
}

// Round 3
// 106.014 us; speedup vs baseline: 3.7989x; 1.2077x over previous
//
#include <hip/hip_runtime.h>
#include <hip/hip_bf16.h>
#include <hip/hip_fp16.h>

// out[4096,128] = bias + P @ W, P built on the fly from products of x-subsets
constexpr int B_   = 4096;
constexpr int C_   = 128;
constexpr int K1   = 32;
constexpr int K2   = 496;
constexpr int K3   = 4960;
constexpr int KTOT = K1 + K2 + K3;   // 5488
constexpr int KPAD = 5632;           // pad entries produce p=0, w=0

constexpr int SPLITK = 16;
constexpr int KSEG   = KPAD / SPLITK;  // 352
constexpr int KC     = 32;
constexpr int CHUNKS = KSEG / KC;      // 11
constexpr int BM     = 64;

constexpr int XS = 35;   // x_s row stride (floats), odd -> conflict-free
constexpr int PW = 40;   // P_s/W_s k-stride (bf16): 80 B, odd superbank -> conflict-free b128

typedef __attribute__((ext_vector_type(8))) short bf16x8;
typedef __attribute__((ext_vector_type(4))) float f32x4;

// ws layout (total ~18.4 MB)
constexpr size_t WS_IDX  = 0;         // int4[5632]            = 90112 B
constexpr size_t WS_WT   = 98304;     // ushort[128*5632]      = 1441792 B
constexpr size_t WS_PART = 1572864;   // __half[16*4096*128]   = 16777216 B

// one prep kernel: blocks 0..351 transpose W -> bf16 [c][k]; blocks 352..373 build u_idx
__global__ __launch_bounds__(256)
void prep_all(const int* __restrict__ idx1,
              const int* __restrict__ idx2,
              const int* __restrict__ idx3,
              const float* __restrict__ W1,
              const float* __restrict__ W2,
              const float* __restrict__ W3,
              int4* __restrict__ u_idx,
              ushort* __restrict__ Wb)
{
    const int b = blockIdx.x, t = threadIdx.x;
    if (b < 352) {
        // 64k x 32c tile transpose, fp32 -> bf16
        __shared__ ushort tile[64 * 33];
        const int k0 = (b >> 2) * 64, c0 = (b & 3) * 32;
        #pragma unroll
        for (int p = 0; p < 8; ++p) {
            int e  = p * 256 + t;
            int kk = e >> 5, c = e & 31;
            int k  = k0 + kk;
            float v = 0.f;
            if (k < K1)           v = W1[k * C_ + c0 + c];
            else if (k < K1 + K2) v = W2[(k - K1) * C_ + c0 + c];
            else if (k < KTOT)    v = W3[(k - K1 - K2) * C_ + c0 + c];
            __hip_bfloat16 h = __float2bfloat16(v);
            tile[kk * 33 + c] = *reinterpret_cast<ushort*>(&h);
        }
        __syncthreads();
        #pragma unroll
        for (int p = 0; p < 8; ++p) {
            int e  = p * 256 + t;
            int c  = e >> 6, kk = e & 63;
            Wb[(size_t)(c0 + c) * KPAD + k0 + kk] = tile[kk * 33 + c];
        }
    } else {
        int i = (b - 352) * 256 + t;   // 22*256 = 5632 exactly
        int4 v; v.w = 0;
        if (i < K1)            { v.x = idx1[i];       v.y = 32; v.z = 32; }   // x_s[32]=1.0
        else if (i < K1 + K2)  { int j = i - K1;      v.x = idx2[2*j]; v.y = idx2[2*j+1]; v.z = 32; }
        else if (i < KTOT)     { int j = i - K1 - K2; v.x = idx3[3*j]; v.y = idx3[3*j+1]; v.z = idx3[3*j+2]; }
        else                   { v.x = 33; v.y = 33; v.z = 33; }              // x_s[33]=0.0
        u_idx[i] = v;
    }
}

// main: fused product construction + bf16 MFMA, split-K, fp16 partial stores (no atomics)
__global__ __launch_bounds__(256, 4)
void poly_mfma(const float* __restrict__ x,
               const int4* __restrict__ u_idx,
               const ushort* __restrict__ Wb,
               __half* __restrict__ part)
{
    __shared__ float  x_s[BM * XS];
    __shared__ ushort P_s[BM * PW];
    __shared__ ushort W_s[C_ * PW];

    const int t    = threadIdx.x;
    const int row0 = blockIdx.x * BM;
    const int kbeg = blockIdx.y * KSEG;

    #pragma unroll
    for (int p = 0; p < 2; ++p) {
        int e = p * 256 + t;
        int r = e >> 3, q = e & 7;
        float4 v = ((const float4*)x)[(size_t)(row0 + r) * 8 + q];
        float* d = &x_s[r * XS + q * 4];
        d[0] = v.x; d[1] = v.y; d[2] = v.z; d[3] = v.w;
    }
    if (t < BM) { x_s[t * XS + 32] = 1.0f; x_s[t * XS + 33] = 0.0f; }

    f32x4 acc[4][2];
    #pragma unroll
    for (int rt = 0; rt < 4; ++rt)
        #pragma unroll
        for (int ct = 0; ct < 2; ++ct) acc[rt][ct] = (f32x4){0.f, 0.f, 0.f, 0.f};

    const int lane = t & 63;
    const int w    = t >> 6;
    const int m    = lane & 15;
    const int kg   = lane >> 4;
    const float* xr = &x_s[lane * XS];

    for (int ch = 0; ch < CHUNKS; ++ch) {
        const int kc = kbeg + ch * KC;
        __syncthreads();

        // stage W^T chunk: W_s[c][0..31]
        #pragma unroll
        for (int p = 0; p < 2; ++p) {
            int e = p * 256 + t;
            int c = e >> 2, g = e & 3;
            *(uint4*)&W_s[c * PW + g * 8] =
                *(const uint4*)&Wb[(size_t)c * KPAD + kc + g * 8];
        }

        // products: wave w owns k-run [kc+w*8, kc+w*8+8), row = lane
        {
            int pa = -1, pb = -1;
            float pab = 0.f;
            union { ushort us[8]; uint4 v; } pk;
            #pragma unroll
            for (int i = 0; i < 8; ++i) {
                int4 id = u_idx[kc + w * 8 + i];
                if (id.x != pa || id.y != pb) { pab = xr[id.x] * xr[id.y]; pa = id.x; pb = id.y; }
                float p = pab * xr[id.z];
                __hip_bfloat16 h = __float2bfloat16(p);
                pk.us[i] = *reinterpret_cast<ushort*>(&h);
            }
            *(uint4*)&P_s[lane * PW + w * 8] = pk.v;
        }
        __syncthreads();

        bf16x8 a[4], bfr[2];
        #pragma unroll
        for (int rt = 0; rt < 4; ++rt)
            a[rt] = *(const bf16x8*)&P_s[(rt * 16 + m) * PW + kg * 8];
        #pragma unroll
        for (int ct = 0; ct < 2; ++ct)
            bfr[ct] = *(const bf16x8*)&W_s[(w * 32 + ct * 16 + m) * PW + kg * 8];
        #pragma unroll
        for (int rt = 0; rt < 4; ++rt)
            #pragma unroll
            for (int ct = 0; ct < 2; ++ct)
                acc[rt][ct] = __builtin_amdgcn_mfma_f32_16x16x32_bf16(
                    a[rt], bfr[ct], acc[rt][ct], 0, 0, 0);
    }

    // epilogue: streaming fp16 partial stores (no atomics, no RMW)
    __half* pp = part + (size_t)blockIdx.y * (B_ * C_);
    const int rq = lane >> 4;           // C/D: col = lane&15, row = rq*4 + i
    #pragma unroll
    for (int rt = 0; rt < 4; ++rt)
        #pragma unroll
        for (int ct = 0; ct < 2; ++ct) {
            int col = w * 32 + ct * 16 + m;
            #pragma unroll
            for (int i = 0; i < 4; ++i) {
                int row = row0 + rt * 16 + rq * 4 + i;
                pp[(size_t)row * C_ + col] = __float2half(acc[rt][ct][i]);
            }
        }
}

// reduce: out = bias + sum_s part[s]
__global__ __launch_bounds__(256)
void reduce_k(const __half* __restrict__ part,
              const float* __restrict__ bias,
              float* __restrict__ out)
{
    int i = (blockIdx.x * 256 + threadIdx.x) * 8;   // 8 consecutive elements
    const float4* bp = (const float4*)&bias[i & (C_ - 1)];
    float4 b0 = bp[0], b1 = bp[1];
    float s[8] = {b0.x, b0.y, b0.z, b0.w, b1.x, b1.y, b1.z, b1.w};
    #pragma unroll
    for (int sp = 0; sp < SPLITK; ++sp) {
        uint4 v = *(const uint4*)&part[(size_t)sp * (B_ * C_) + i];
        const __half2* h2 = (const __half2*)&v;
        #pragma unroll
        for (int j = 0; j < 4; ++j) {
            float2 f = __half22float2(h2[j]);
            s[2*j] += f.x; s[2*j+1] += f.y;
        }
    }
    float4 o0 = {s[0], s[1], s[2], s[3]};
    float4 o1 = {s[4], s[5], s[6], s[7]};
    *(float4*)&out[i]     = o0;
    *(float4*)&out[i + 4] = o1;
}

extern "C" void kernel_launch(void* const* d_in, const int* in_sizes, int n_in,
                              void* d_out, int out_size, void* d_ws, size_t ws_size,
                              hipStream_t stream)
{
    const float* x    = (const float*)d_in[0];
    const float* bias = (const float*)d_in[1];
    const float* W1   = (const float*)d_in[2];
    const float* W2   = (const float*)d_in[3];
    const float* W3   = (const float*)d_in[4];
    const int*   idx1 = (const int*)d_in[5];
    const int*   idx2 = (const int*)d_in[6];
    const int*   idx3 = (const int*)d_in[7];
    float* out = (float*)d_out;

    int4*   u_idx = (int4*)((char*)d_ws + WS_IDX);
    ushort* Wb    = (ushort*)((char*)d_ws + WS_WT);
    __half* partp = (__half*)((char*)d_ws + WS_PART);

    prep_all<<<374, 256, 0, stream>>>(idx1, idx2, idx3, W1, W2, W3, u_idx, Wb);

    dim3 grid(B_ / BM, SPLITK);
    poly_mfma<<<grid, 256, 0, stream>>>(x, u_idx, Wb, partp);

    reduce_k<<<(B_ * C_) / 8 / 256, 256, 0, stream>>>(partp, bias, out);
}